// Round 5
// baseline (220.127 us; speedup 1.0000x reference)
//
#include <hip/hip_runtime.h>
#include <hip/hip_bf16.h>

#define TQ 4096   // reference sequence length
#define LK 4096   // modality sequence length
#define QT 16     // queries per attn block

// ---------- dtype-polymorphic load/store (decided at runtime by sniff) ------
template<bool BF> __device__ __forceinline__ float ld(const void* p, int i);
template<> __device__ __forceinline__ float ld<true>(const void* p, int i) {
    return __bfloat162float(((const __hip_bfloat16*)p)[i]);
}
template<> __device__ __forceinline__ float ld<false>(const void* p, int i) {
    return ((const float*)p)[i];
}
template<bool BF> __device__ __forceinline__ void st(void* p, int i, float v);
template<> __device__ __forceinline__ void st<true>(void* p, int i, float v) {
    ((__hip_bfloat16*)p)[i] = __float2bfloat16(v);
}
template<> __device__ __forceinline__ void st<false>(void* p, int i, float v) {
    ((float*)p)[i] = v;
}
template<bool BF> __device__ __forceinline__ void st4(void* p, int i, float4 v);
template<> __device__ __forceinline__ void st4<true>(void* p, int i, float4 v) {
    __hip_bfloat16* o = (__hip_bfloat16*)p + i;
    o[0] = __float2bfloat16(v.x); o[1] = __float2bfloat16(v.y);
    o[2] = __float2bfloat16(v.z); o[3] = __float2bfloat16(v.w);
}
template<> __device__ __forceinline__ void st4<false>(void* p, int i, float4 v) {
    *(float4*)((float*)p + i) = v;
}

// ---------- inline dtype sniff (per-wave, no extra kernel) -------------------
// ref_time sorted uniform [0,1). EVEN half-words: bf16 input -> full elements
// in [0,1]; f32 input -> low mantissa bits (random; all-pass prob ~5e-20).
__device__ __forceinline__ bool sniff_bf16(const void* ref_time) {
    const int lane = threadIdx.x & 63;
    bool ok = true;
    if (lane < 32) {
        float v = __bfloat162float(((const __hip_bfloat16*)ref_time)[2 * lane]);
        ok = (v >= 0.0f) && (v <= 1.0f);   // NaN fails
    }
    return __ballot(ok) == ~0ULL;
}

// ---------- binary searches ----------
template<bool BF>
__device__ int ub_time(const void* arr, int n, float key) {
    int lo = 0, hi = n;
    while (lo < hi) { int mid = (lo + hi) >> 1; if (ld<BF>(arr, mid) <= key) lo = mid + 1; else hi = mid; }
    return lo;
}
__device__ int lb_int(const int* arr, int n, int key) {
    int lo = 0, hi = n;
    while (lo < hi) { int mid = (lo + hi) >> 1; if (arr[mid] < key) lo = mid + 1; else hi = mid; }
    return lo;
}
__device__ int ub_int(const int* arr, int n, int key) {
    int lo = 0, hi = n;
    while (lo < hi) { int mid = (lo + hi) >> 1; if (arr[mid] <= key) lo = mid + 1; else hi = mid; }
    return lo;
}

// ---------- prep: one wave per 4 queries: shfl matvec -> (alpha,beta); 24
// lanes do one binary search each for c/s/e of both modalities. ----------
template<bool BF>
__device__ void prep_body(
    const void* ref_data, const void* ref_time, const int* ref_idx,
    const void* m1_time, const int* m1_idx, const void* m2_time, const int* m2_idx,
    const void* Wq, const void* bq,
    const void* Wk1, const void* bk1, const void* Wk2, const void* bk2,
    float* alpha1, float* beta1, float* alpha2, float* beta2,
    int* c1, int* s1, int* e1, int* c2, int* s2, int* e2)
{
    const int lane = threadIdx.x;        // 0..63
    const int t0 = blockIdx.x * 4;

    float rq[4];
    #pragma unroll
    for (int k = 0; k < 4; ++k) rq[k] = ld<BF>(ref_data, (t0 + k) * 64 + lane);

    const float bq0 = ld<BF>(bq, lane), bq1 = ld<BF>(bq, 64 + lane);
    float a0[4], a1[4];
    #pragma unroll
    for (int k = 0; k < 4; ++k) { a0[k] = bq0; a1[k] = bq1; }

    #pragma unroll 16
    for (int i = 0; i < 64; ++i) {
        const float w0 = ld<BF>(Wq, i * 128 + lane);
        const float w1 = ld<BF>(Wq, i * 128 + 64 + lane);
        #pragma unroll
        for (int k = 0; k < 4; ++k) {
            const float x = __shfl(rq[k], i);
            a0[k] = fmaf(x, w0, a0[k]);
            a1[k] = fmaf(x, w1, a1[k]);
        }
    }

    // beta  = sum_{j>=1} qp[j]*Wk[j-1] + Wk[127]
    // alpha = qp[0] - sum_{j>=1} qp[j]*bk[j-1] - bk[127]
    const float wk1lo = (lane >= 1) ? ld<BF>(Wk1, lane - 1) : 0.0f;
    const float wk1hi = ld<BF>(Wk1, lane + 63);
    const float bk1lo = (lane >= 1) ? ld<BF>(bk1, lane - 1) : 0.0f;
    const float bk1hi = ld<BF>(bk1, lane + 63);
    const float wk2lo = (lane >= 1) ? ld<BF>(Wk2, lane - 1) : 0.0f;
    const float wk2hi = ld<BF>(Wk2, lane + 63);
    const float bk2lo = (lane >= 1) ? ld<BF>(bk2, lane - 1) : 0.0f;
    const float bk2hi = ld<BF>(bk2, lane + 63);
    const float wk1sp = ld<BF>(Wk1, 127), bk1sp = ld<BF>(bk1, 127);
    const float wk2sp = ld<BF>(Wk2, 127), bk2sp = ld<BF>(bk2, 127);
    const float sp = (lane == 0) ? 1.0f : 0.0f;

    float red[16];
    #pragma unroll
    for (int k = 0; k < 4; ++k) {
        red[k * 4 + 0] = fmaf(a0[k], wk1lo, fmaf(a1[k], wk1hi, sp * wk1sp));
        red[k * 4 + 1] = sp * (a0[k] - bk1sp) - a0[k] * bk1lo - a1[k] * bk1hi;
        red[k * 4 + 2] = fmaf(a0[k], wk2lo, fmaf(a1[k], wk2hi, sp * wk2sp));
        red[k * 4 + 3] = sp * (a0[k] - bk2sp) - a0[k] * bk2lo - a1[k] * bk2hi;
    }
    #pragma unroll
    for (int o = 32; o >= 1; o >>= 1) {
        #pragma unroll
        for (int r = 0; r < 16; ++r) red[r] += __shfl_xor(red[r], o);
    }
    if (lane < 4) {
        const int t = t0 + lane;
        beta1[t]  = red[lane * 4 + 0];
        alpha1[t] = red[lane * 4 + 1];
        beta2[t]  = red[lane * 4 + 2];
        alpha2[t] = red[lane * 4 + 3];
    }

    if (lane < 24) {
        const int kind = lane >> 2, k = lane & 3, t = t0 + k;
        switch (kind) {
            case 0: c1[t] = ub_time<BF>(m1_time, LK, ld<BF>(ref_time, t)); break;
            case 1: c2[t] = ub_time<BF>(m2_time, LK, ld<BF>(ref_time, t)); break;
            case 2: s1[t] = lb_int(m1_idx, LK, ref_idx[t]); break;
            case 3: e1[t] = ub_int(m1_idx, LK, ref_idx[t]); break;
            case 4: s2[t] = lb_int(m2_idx, LK, ref_idx[t]); break;
            case 5: e2[t] = ub_int(m2_idx, LK, ref_idx[t]); break;
        }
    }
}

__global__ __launch_bounds__(64) void prep_kernel(
    const void* ref_data, const void* ref_time, const int* ref_idx,
    const void* m1_time, const int* m1_idx, const void* m2_time, const int* m2_idx,
    const void* Wq, const void* bq,
    const void* Wk1, const void* bk1, const void* Wk2, const void* bk2,
    float* alpha1, float* beta1, float* alpha2, float* beta2,
    int* c1, int* s1, int* e1, int* c2, int* s2, int* e2)
{
    if (sniff_bf16(ref_time))
        prep_body<true>(ref_data, ref_time, ref_idx, m1_time, m1_idx, m2_time, m2_idx,
                        Wq, bq, Wk1, bk1, Wk2, bk2,
                        alpha1, beta1, alpha2, beta2, c1, s1, e1, c2, s2, e2);
    else
        prep_body<false>(ref_data, ref_time, ref_idx, m1_time, m1_idx, m2_time, m2_idx,
                         Wq, bq, Wk1, bk1, Wk2, bk2,
                         alpha1, beta1, alpha2, beta2, c1, s1, e1, c2, s2, e2);
}

// ---------- vproj: 16 rows/block, LDS-staged rows, unrolled K, 8 acc/thread --
template<bool BF, int K, int DM>
__device__ void vproj_tile(const void* md, const void* Wv, const void* bv,
                           float* V, float* X, float* smd)
{
    const int ST = DM + 2;                 // float4-aligned row stride
    const int tid = threadIdx.x;           // 256
    const int l0 = blockIdx.x * 16;

    {   // stage 16 rows
        const int r = tid >> 4, ii = tid & 15;
        for (int i = ii; i < DM; i += 16)
            smd[r * ST + i] = ld<BF>(md, (l0 + r) * DM + i);
    }
    __syncthreads();

    const int col = tid & 127, rg = tid >> 7;
    float acc[8];
    const float b = ld<BF>(bv, col);
    #pragma unroll
    for (int r = 0; r < 8; ++r) acc[r] = b;

    #pragma unroll 8
    for (int i = 0; i < K; i += 4) {
        const float w0 = ld<BF>(Wv, (i + 0) * 128 + col);
        const float w1 = ld<BF>(Wv, (i + 1) * 128 + col);
        const float w2 = ld<BF>(Wv, (i + 2) * 128 + col);
        const float w3 = ld<BF>(Wv, (i + 3) * 128 + col);
        #pragma unroll
        for (int r = 0; r < 8; ++r) {
            const float4 mv = *(const float4*)&smd[(rg * 8 + r) * ST + i];
            acc[r] = fmaf(mv.x, w0, fmaf(mv.y, w1, fmaf(mv.z, w2, fmaf(mv.w, w3, acc[r]))));
        }
    }
    #pragma unroll
    for (int r = 0; r < 8; ++r)
        V[(size_t)(l0 + rg * 8 + r) * 128 + col] = acc[r];
    if (tid < 16) X[l0 + tid] = smd[tid * ST + DM - 1];
}

template<bool BF>
__device__ void vproj_body(const void* m1_data, const void* Wv1, const void* bv1,
                           const void* m2_data, const void* Wv2, const void* bv2,
                           float* V1, float* V2, float* X1, float* X2, float* smd)
{
    if (blockIdx.y == 0) vproj_tile<BF, 128, 130>(m1_data, Wv1, bv1, V1, X1, smd);
    else                 vproj_tile<BF, 64, 66>(m2_data, Wv2, bv2, V2, X2, smd);
}

__global__ __launch_bounds__(256) void vproj_kernel(
    const void* __restrict__ ref_time,
    const void* m1_data, const void* Wv1, const void* bv1,
    const void* m2_data, const void* Wv2, const void* bv2,
    float* V1, float* V2, float* X1, float* X2)
{
    __shared__ float smd[16 * 132];
    if (sniff_bf16(ref_time))
        vproj_body<true>(m1_data, Wv1, bv1, m2_data, Wv2, bv2, V1, V2, X1, X2, smd);
    else
        vproj_body<false>(m1_data, Wv1, bv1, m2_data, Wv2, bv2, V1, V2, X1, X2, smd);
}

// ---------- attn v3: register-resident weights, no LDS in hot loop ----------
// QT=16 queries/block, 256 threads, 2 queries/thread, V/X straight from L2.
struct ASh {
    float sAl[QT], sBe[QT], sM[QT], sZ[QT];
    int sS[QT], sCM[QT], sN[QT];
};

template<bool BF>
__device__ void attn_body(
    const float* __restrict__ alpha, const float* __restrict__ beta,
    const int* __restrict__ cA, const int* __restrict__ sA, const int* __restrict__ eA,
    const float* __restrict__ V, const float* __restrict__ X,
    float lt, void* out, int mod, ASh& sh)
{
    const int tid = threadIdx.x;            // 256
    const int t0 = blockIdx.x * QT;
    const float scale = __expf(-lt);

    if (tid < QT) {
        const int t = t0 + tid;
        int s = sA[t], e = eA[t];
        const int c = cA[t];
        if (s == e) { s = 0; e = LK; }      // fully-masked fallback
        sh.sS[tid] = s;
        sh.sCM[tid] = min(c, e);
        sh.sN[tid] = (e > c) ? (e - max(s, c)) : 0;
        sh.sAl[tid] = alpha[t];
        sh.sBe[tid] = beta[t];
    }
    __syncthreads();

    // Phase A: online-softmax (m, Z) per query; 16 threads/query, shfl merge.
    {
        const int q = tid >> 4, k = tid & 15;
        const int s = sh.sS[q], cm = sh.sCM[q];
        const float al = sh.sAl[q], be = sh.sBe[q];
        float m = -3.0e38f, z = 0.0f;
        for (int j = s + k; j < cm; j += 16) {
            const float qk = fmaf(-be, X[j], al);
            const float a = -(qk * qk) * scale;
            if (a > m) { z *= __expf(m - a); m = a; }
            z += __expf(a - m);
        }
        #pragma unroll
        for (int o = 8; o >= 1; o >>= 1) {
            const float mo = __shfl_xor(m, o);
            const float zo = __shfl_xor(z, o);
            const float mm = fmaxf(m, mo);
            z = z * __expf(m - mm) + zo * __expf(mo - mm);
            m = mm;
        }
        if (k == 0) {
            const int nnc = sh.sN[q];
            if (nnc > 0) { z = fmaf(z, __expf(m), (float)nnc); m = 0.0f; }
            sh.sM[q] = m;
            sh.sZ[q] = fmaxf(z, 1.0e-20f);
        }
    }
    __syncthreads();

    // Main loop: thread owns 2 queries x 4 cols; w recomputed in registers.
    const int d4 = tid & 31;                // float4 column group
    const int q0 = (tid >> 5) * 2, q1 = q0 + 1;
    const float al0 = sh.sAl[q0], be0 = sh.sBe[q0], m0 = sh.sM[q0];
    const float al1 = sh.sAl[q1], be1 = sh.sBe[q1], m1 = sh.sM[q1];
    const int s0 = sh.sS[q0], cm0 = sh.sCM[q0];
    const int s1 = sh.sS[q1], cm1 = sh.sCM[q1];
    const int jlo = min(s0, s1), jhi = max(cm0, cm1);

    float4 acc0 = {0, 0, 0, 0}, acc1 = {0, 0, 0, 0};
    const float4* __restrict__ Vg = (const float4*)V;
    #pragma unroll 4
    for (int j = jlo; j < jhi; ++j) {
        const float x = X[j];
        const float4 v = Vg[j * 32 + d4];
        const float qk0 = fmaf(-be0, x, al0);
        float w0 = __expf(fmaf(-qk0 * qk0, scale, -m0));
        w0 = (j >= s0 && j < cm0) ? w0 : 0.0f;
        const float qk1 = fmaf(-be1, x, al1);
        float w1 = __expf(fmaf(-qk1 * qk1, scale, -m1));
        w1 = (j >= s1 && j < cm1) ? w1 : 0.0f;
        acc0.x = fmaf(w0, v.x, acc0.x);
        acc0.y = fmaf(w0, v.y, acc0.y);
        acc0.z = fmaf(w0, v.z, acc0.z);
        acc0.w = fmaf(w0, v.w, acc0.w);
        acc1.x = fmaf(w1, v.x, acc1.x);
        acc1.y = fmaf(w1, v.y, acc1.y);
        acc1.z = fmaf(w1, v.z, acc1.z);
        acc1.w = fmaf(w1, v.w, acc1.w);
    }
    const float i0 = 1.0f / sh.sZ[q0];
    const float i1 = 1.0f / sh.sZ[q1];
    const float4 o0 = {acc0.x * i0, acc0.y * i0, acc0.z * i0, acc0.w * i0};
    const float4 o1 = {acc1.x * i1, acc1.y * i1, acc1.z * i1, acc1.w * i1};
    st4<BF>(out, (t0 + q0) * 256 + mod * 128 + d4 * 4, o0);
    st4<BF>(out, (t0 + q1) * 256 + mod * 128 + d4 * 4, o1);
}

__global__ __launch_bounds__(256) void attn_kernel(
    const void* __restrict__ ref_time,
    const float* __restrict__ alpha1, const float* __restrict__ beta1,
    const float* __restrict__ alpha2, const float* __restrict__ beta2,
    const int* __restrict__ c1, const int* __restrict__ s1, const int* __restrict__ e1,
    const int* __restrict__ c2, const int* __restrict__ s2, const int* __restrict__ e2,
    const float* __restrict__ V1, const float* __restrict__ V2,
    const float* __restrict__ X1, const float* __restrict__ X2,
    const void* log_tau1, const void* log_tau2, void* out)
{
    __shared__ ASh sh;
    const int mod = blockIdx.y;
    const bool bf = sniff_bf16(ref_time);
    const float* alpha = mod ? alpha2 : alpha1;
    const float* beta  = mod ? beta2  : beta1;
    const int* cA = mod ? c2 : c1;
    const int* sA = mod ? s2 : s1;
    const int* eA = mod ? e2 : e1;
    const float* V = mod ? V2 : V1;
    const float* X = mod ? X2 : X1;
    const void* ltp = mod ? log_tau2 : log_tau1;
    if (bf)
        attn_body<true>(alpha, beta, cA, sA, eA, V, X, ld<true>(ltp, 0), out, mod, sh);
    else
        attn_body<false>(alpha, beta, cA, sA, eA, V, X, ld<false>(ltp, 0), out, mod, sh);
}

extern "C" void kernel_launch(void* const* d_in, const int* in_sizes, int n_in,
                              void* d_out, int out_size, void* d_ws, size_t ws_size,
                              hipStream_t stream)
{
    const void* ref_data = d_in[0];
    const void* ref_time = d_in[1];
    const int*  ref_idx  = (const int*)d_in[2];
    const void* m1_data  = d_in[3];
    const void* m1_time  = d_in[4];
    const int*  m1_idx   = (const int*)d_in[5];
    const void* m2_data  = d_in[6];
    const void* m2_time  = d_in[7];
    const int*  m2_idx   = (const int*)d_in[8];
    const void* Wq  = d_in[9];
    const void* bq  = d_in[10];
    const void* Wk1 = d_in[11];
    const void* bk1 = d_in[12];
    const void* Wv1 = d_in[13];
    const void* bv1 = d_in[14];
    const void* Wk2 = d_in[15];
    const void* bk2 = d_in[16];
    const void* Wv2 = d_in[17];
    const void* bv2 = d_in[18];
    const void* log_tau1 = d_in[19];
    const void* log_tau2 = d_in[20];

    float* ws = (float*)d_ws;
    float* alpha1 = ws + 0 * TQ;
    float* beta1  = ws + 1 * TQ;
    float* alpha2 = ws + 2 * TQ;
    float* beta2  = ws + 3 * TQ;
    int*   c1 = (int*)(ws + 4 * TQ);
    int*   c2 = (int*)(ws + 5 * TQ);
    int*   s1 = (int*)(ws + 6 * TQ);
    int*   e1 = (int*)(ws + 7 * TQ);
    int*   s2 = (int*)(ws + 8 * TQ);
    int*   e2 = (int*)(ws + 9 * TQ);
    float* X1 = ws + 10 * TQ;
    float* X2 = ws + 11 * TQ;
    float* V1 = ws + 12 * TQ;                  // 4096*128 floats
    float* V2 = V1 + (size_t)LK * 128;         // 4096*128 floats

    prep_kernel<<<dim3(TQ / 4), dim3(64), 0, stream>>>(
        ref_data, ref_time, ref_idx, m1_time, m1_idx, m2_time, m2_idx,
        Wq, bq, Wk1, bk1, Wk2, bk2,
        alpha1, beta1, alpha2, beta2, c1, s1, e1, c2, s2, e2);

    vproj_kernel<<<dim3(LK / 16, 2), dim3(256), 0, stream>>>(
        ref_time, m1_data, Wv1, bv1, m2_data, Wv2, bv2, V1, V2, X1, X2);

    attn_kernel<<<dim3(TQ / QT, 2), dim3(256), 0, stream>>>(
        ref_time, alpha1, beta1, alpha2, beta2, c1, s1, e1, c2, s2, e2,
        V1, V2, X1, X2, log_tau1, log_tau2, (void*)d_out);
}